// Round 9
// baseline (2199.547 us; speedup 1.0000x reference)
//
#include <hip/hip_runtime.h>
#include <hip/hip_bf16.h>

// SwiGLU FFN, fp32 in/out: out = clamp(silu(x@w1t) * (x@w3t), ±65504) @ w2t
// x[8192,3072], w13[16384,3072] (rows 0..8191 = w3 -> x3, 8192.. = w1 -> x1), w2[3072,8192].
// bf16 compute via cvt pre-pass; mfma_f32_16x16x32_bf16; fp32 accum; fp32 out.
// Round-9: gateup back to BM=256 (intensity fix for R8's fetch-bound regression) with
//   A-OPERAND DIRECT FROM GLOBAL (VGPR, L1/L2-served; per-mf reload interleaved in the
//   MFMA block) and ONLY B3/B1 in LDS -> 32KB/buf x 3 bufs = 96KB -> proven
//   1-barrier / counted-VMCNT(4) / depth-2 skeleton at full tile size.
// Down = R6/R7-proven down11 (67% MfmaUtil), unchanged.
// 16x16x32 frags + row&7 slot swizzle for LDS B (0 conflicts).

typedef __attribute__((ext_vector_type(8))) __bf16 bf16x8;
typedef __attribute__((ext_vector_type(4))) float f32x4;

#define GLD_LDS16(gptr, lptr)                                                        \
  __builtin_amdgcn_global_load_lds(                                                  \
      (const __attribute__((address_space(1))) void*)(gptr),                         \
      (__attribute__((address_space(3))) void*)(lptr), 16, 0, 0)

#define VMCNT(n) asm volatile("s_waitcnt vmcnt(" #n ")" ::: "memory")
#define BAR()    __builtin_amdgcn_s_barrier()

#define MFMA16(a, b, c) __builtin_amdgcn_mfma_f32_16x16x32_bf16((a), (b), (c), 0, 0, 0)

__device__ __forceinline__ __bf16 bfr(float f) {  // RNE fp32->bf16
  unsigned int u = __builtin_bit_cast(unsigned int, f);
  unsigned short r = (unsigned short)((u + 0x7FFFu + ((u >> 16) & 1u)) >> 16);
  return __builtin_bit_cast(__bf16, r);
}

// ---------------- fp32 -> bf16 conversion pre-pass ----------------
__global__ __launch_bounds__(256)
void k_cvt(const float* __restrict__ src, unsigned short* __restrict__ dst, long n) {
  long i = ((long)blockIdx.x * 256 + threadIdx.x) * 8;
  const long stride = (long)gridDim.x * 256 * 8;
  for (; i < n; i += stride) {
    float4 f0 = *(const float4*)(src + i);
    float4 f1 = *(const float4*)(src + i + 4);
    bf16x8 o;
    o[0] = bfr(f0.x); o[1] = bfr(f0.y); o[2] = bfr(f0.z); o[3] = bfr(f0.w);
    o[4] = bfr(f1.x); o[5] = bfr(f1.y); o[6] = bfr(f1.z); o[7] = bfr(f1.w);
    *(bf16x8*)(dst + i) = o;
  }
}

// ============ Kernel 1: fused gate/up, 256x128 g-tile, BK=64, A-direct, B 3-buf ========
// 8 waves (2M x 4N); per-wave: 128 A-rows (VGPR, global-direct) x (32 B3 + 32 B1 cols).
// Per K-tile: VMCNT(4); BAR; ds_read 8 B-frags; prio1; 8x{8 MFMA + reload aa[mf](c+1)};
//             prio0; stage B(c+2) (4 gload_lds).  One barrier, no drain.
__global__ __launch_bounds__(512, 2)
void k_gateup15(const unsigned short* __restrict__ X,
                const unsigned short* __restrict__ W13,
                __hip_bfloat16* __restrict__ G)
{
  constexpr int K = 3072, LDG = 8192, NT = K / 64;
  __shared__ unsigned short lds[49152];  // 96KB: 3 bufs x (B3[128][64] | B1[128][64])
                                         // buf e @ e*16384; B3 @ +0, B1 @ +8192

  const int t = threadIdx.x, l = t & 63, wid = t >> 6;
  const int wm = wid >> 2, wn = wid & 3;          // 2M x 4N
  const int l15 = l & 15, lhi = l >> 4, sw = l15 & 7;

  const int bid = blockIdx.x;                     // 2048 blocks, XCD-chunked (8*256)
  const int swz = (bid & 7) * 256 + (bid >> 3);
  const int mb = swz >> 6, nb = swz & 63;

  // --- A direct-from-global lane base: row = mb*256 + wm*128 + mf*16 + l15 ---
  const unsigned short* ap = X + (size_t)(mb * 256 + wm * 128 + l15) * K + lhi * 8;

  // --- B staging (pre-swizzled global source, linear gload_lds dest) ---
  const int srow = t >> 3;                        // 0..63
  const int scol = ((t & 7) ^ (srow & 7)) * 8;
  const unsigned short* b3 = W13 + (size_t)(nb * 128 + srow) * K + scol;
  const unsigned short* b1 = W13 + (size_t)(8192 + nb * 128 + srow) * K + scol;
  const int lo = t * 8;

#define STB(e, kt) do {                                                        \
    GLD_LDS16(b3 + (kt),                 lds + (e) * 16384 + lo);              \
    GLD_LDS16(b3 + (size_t)64 * K + (kt), lds + (e) * 16384 + 4096 + lo);      \
    GLD_LDS16(b1 + (kt),                 lds + (e) * 16384 + 8192 + lo);       \
    GLD_LDS16(b1 + (size_t)64 * K + (kt), lds + (e) * 16384 + 12288 + lo);     \
  } while (0)

  f32x4 acc3[8][2], acc1[8][2];
#pragma unroll
  for (int m = 0; m < 8; ++m)
#pragma unroll
    for (int n = 0; n < 2; ++n) {
      acc3[m][n] = (f32x4){0.f, 0.f, 0.f, 0.f};
      acc1[m][n] = (f32x4){0.f, 0.f, 0.f, 0.f};
    }

  // prologue: A(0) into regs (16 loads), then stage B(0), B(1)
  bf16x8 aa[8][2];
#pragma unroll
  for (int mf = 0; mf < 8; ++mf)
#pragma unroll
    for (int kk = 0; kk < 2; ++kk)
      aa[mf][kk] = *(const bf16x8*)(ap + (size_t)(mf * 16) * K + kk * 32);
  STB(0, 0);
  STB(1, 64);

  for (int c = 0; c < NT; ++c) {
    const int e = c % 3;
    const int eS = (c + 2) % 3;                    // buffer of tile c-1 (reads retired)
    const int k2 = (c + 2 < NT ? c + 2 : c + 2 - NT) * 64;
    const int kn = (c + 1 < NT ? c + 1 : 0) * 64;  // A source for next tile
    const int Bb = e * 16384;

    // entry: A(c) (issued mid prev iter) + B(c) (issued 2 iters ago) landed;
    // B(c+1)'s 4 stays in flight
    VMCNT(4);
    BAR();

    bf16x8 r3[2][2], r1[2][2];
#pragma unroll
    for (int nf = 0; nf < 2; ++nf)
#pragma unroll
      for (int kk = 0; kk < 2; ++kk) {
        const int row = wn * 32 + nf * 16 + l15;
        r3[nf][kk] = *(const bf16x8*)(lds + Bb + row * 64 + ((kk * 4 + lhi) ^ sw) * 8);
        r1[nf][kk] = *(const bf16x8*)(lds + Bb + 8192 + row * 64 + ((kk * 4 + lhi) ^ sw) * 8);
      }

    __builtin_amdgcn_s_setprio(1);
#pragma unroll
    for (int mf = 0; mf < 8; ++mf) {
      // 8 MFMAs consuming aa[mf] (A of tile c)
#pragma unroll
      for (int nf = 0; nf < 2; ++nf)
#pragma unroll
        for (int kk = 0; kk < 2; ++kk) {
          acc3[mf][nf] = MFMA16(aa[mf][kk], r3[nf][kk], acc3[mf][nf]);
          acc1[mf][nf] = MFMA16(aa[mf][kk], r1[nf][kk], acc1[mf][nf]);
        }
      // reload aa[mf] with A of tile c+1 (lands by next iter's entry VMCNT)
      aa[mf][0] = *(const bf16x8*)(ap + (size_t)(mf * 16) * K + kn);
      aa[mf][1] = *(const bf16x8*)(ap + (size_t)(mf * 16) * K + 32 + kn);
    }
    __builtin_amdgcn_s_setprio(0);

    // stage B(c+2) last: youngest in-flight loads at next entry -> VMCNT(4) keeps them
    STB(eS, k2);
  }

  // epilogue: g = clamp(silu(x1)*x3). 16x16 C/D: col=l15, row=lhi*4+r
  const int gr0 = mb * 256 + wm * 128;
  const int gc0 = nb * 128 + wn * 32;
#pragma unroll
  for (int mf = 0; mf < 8; ++mf)
#pragma unroll
    for (int nf = 0; nf < 2; ++nf)
#pragma unroll
      for (int r = 0; r < 4; ++r) {
        float h3 = acc3[mf][nf][r];
        float h1 = acc1[mf][nf][r];
        float s  = h1 / (1.f + __expf(-h1));
        float g  = fminf(fmaxf(s * h3, -65504.f), 65504.f);
        G[(size_t)(gr0 + mf * 16 + lhi * 4 + r) * LDG + (gc0 + nf * 16 + l15)] =
            __float2bfloat16(g);
      }
#undef STB
}

// ============ Kernel 2: down proj, 256x128 tile, BK=64, 3-buf, 1 phase/K-tile ============
// 8 waves (4M x 2N), per-wave 64x64, 16x16x32 frags. Proven 67% MfmaUtil — unchanged.
__global__ __launch_bounds__(512, 2)
void k_down11(const unsigned short* __restrict__ Gm,
              const unsigned short* __restrict__ W2,
              float* __restrict__ Out)
{
  constexpr int K = 8192, LDO = 3072, NT = K / 64;
  __shared__ unsigned short lds[73728];  // 144KB: A[3]@0 (16384 ea) | B[3]@49152 (8192 ea)

  const int t = threadIdx.x, l = t & 63, wid = t >> 6;
  const int wm = wid >> 1, wn = wid & 1;          // 4M x 2N
  const int l15 = l & 15, lhi = l >> 4, sw = l15 & 7;

  const int bid = blockIdx.x;                     // 768 blocks
  const int swz = (bid & 7) * 96 + (bid >> 3);
  const int mb = swz / 24, nb = swz % 24;

  const int srow = t >> 3;
  const int scol = ((t & 7) ^ (srow & 7)) * 8;
  const unsigned short* ga = Gm + (size_t)(mb * 256 + srow) * K + scol;
  const unsigned short* wb = W2 + (size_t)(nb * 128 + srow) * K + scol;
  const int lo = t * 8;

#define DST_A(e, kt) do {                                                       \
    GLD_LDS16(ga + (kt),                 lds + (e) * 16384 + lo);               \
    GLD_LDS16(ga + (size_t)64 * K + (kt),  lds + (e) * 16384 + 4096 + lo);      \
    GLD_LDS16(ga + (size_t)128 * K + (kt), lds + (e) * 16384 + 8192 + lo);      \
    GLD_LDS16(ga + (size_t)192 * K + (kt), lds + (e) * 16384 + 12288 + lo);     \
  } while (0)
#define DST_B(e, kt) do {                                                       \
    GLD_LDS16(wb + (kt),                lds + 49152 + (e) * 8192 + lo);         \
    GLD_LDS16(wb + (size_t)64 * K + (kt), lds + 49152 + (e) * 8192 + 4096 + lo); \
  } while (0)

  f32x4 acc[4][4];
#pragma unroll
  for (int mf = 0; mf < 4; ++mf)
#pragma unroll
    for (int nf = 0; nf < 4; ++nf)
      acc[mf][nf] = (f32x4){0.f, 0.f, 0.f, 0.f};

  // prologue: tiles 0,1 (6 loads each)
  DST_B(0, 0);  DST_A(0, 0);
  DST_B(1, 64); DST_A(1, 64);

  for (int c = 0; c < NT; ++c) {
    const int e = c % 3;
    const int eS = (c + 2) % 3;
    const int k2 = (c + 2 < NT ? c + 2 : 0) * 64;

    VMCNT(6);    // tile c's 6 landed (tile c+1's 6 in flight)
    BAR();

    bf16x8 ra[4][2], rb[4][2];
#pragma unroll
    for (int mf = 0; mf < 4; ++mf)
#pragma unroll
      for (int kk = 0; kk < 2; ++kk)
        ra[mf][kk] = *(const bf16x8*)(lds + e * 16384 + (wm * 64 + mf * 16 + l15) * 64 + ((kk * 4 + lhi) ^ sw) * 8);
#pragma unroll
    for (int nf = 0; nf < 4; ++nf)
#pragma unroll
      for (int kk = 0; kk < 2; ++kk)
        rb[nf][kk] = *(const bf16x8*)(lds + 49152 + e * 8192 + (wn * 64 + nf * 16 + l15) * 64 + ((kk * 4 + lhi) ^ sw) * 8);

    // stage tile c+2 into buffer of tile c-1 (reads done before this iter's barrier)
    DST_B(eS, k2);
    DST_A(eS, k2);

    __builtin_amdgcn_s_setprio(1);
#pragma unroll
    for (int mf = 0; mf < 4; ++mf)
#pragma unroll
      for (int nf = 0; nf < 4; ++nf)
#pragma unroll
        for (int kk = 0; kk < 2; ++kk)
          acc[mf][nf] = MFMA16(ra[mf][kk], rb[nf][kk], acc[mf][nf]);
    __builtin_amdgcn_s_setprio(0);
  }

  const int r0 = mb * 256 + wm * 64;
  const int c0 = nb * 128 + wn * 64;
#pragma unroll
  for (int mf = 0; mf < 4; ++mf)
#pragma unroll
    for (int nf = 0; nf < 4; ++nf)
#pragma unroll
      for (int r = 0; r < 4; ++r)
        Out[(size_t)(r0 + mf * 16 + lhi * 4 + r) * LDO + (c0 + nf * 16 + l15)] =
            acc[mf][nf][r];
#undef DST_A
#undef DST_B
}

extern "C" void kernel_launch(void* const* d_in, const int* in_sizes, int n_in,
                              void* d_out, int out_size, void* d_ws, size_t ws_size,
                              hipStream_t stream) {
  const float* x   = (const float*)d_in[0];   // [2,4096,3072] f32
  const float* w13 = (const float*)d_in[1];   // [16384,3072] f32
  const float* w2  = (const float*)d_in[2];   // [3072,8192] f32
  float* out = (float*)d_out;                 // [2,4096,3072] f32

  const long NX = 25165824L, NW13 = 50331648L, NW2 = 25165824L;
  const size_t XB = 50331648, W13B = 100663296, W2B = 50331648;

  unsigned short* xb   = (unsigned short*)d_ws;
  unsigned short* w13b = (unsigned short*)((char*)d_ws + XB);
  unsigned short* w2b  = (unsigned short*)((char*)d_ws + XB + W13B);
  __hip_bfloat16* g    = (__hip_bfloat16*)((char*)d_ws + XB + W13B + W2B);

  k_cvt<<<2048, 256, 0, stream>>>(x,   xb,   NX);
  k_cvt<<<2048, 256, 0, stream>>>(w13, w13b, NW13);
  k_cvt<<<2048, 256, 0, stream>>>(w2,  w2b,  NW2);
  k_gateup15<<<2048, 512, 0, stream>>>(xb, w13b, g);
  k_down11<<<768, 512, 0, stream>>>((const unsigned short*)g, w2b, out);
}

// Round 10
// 1263.325 us; speedup vs baseline: 1.7411x; 1.7411x over previous
//
#include <hip/hip_runtime.h>
#include <hip/hip_bf16.h>

// SwiGLU FFN, fp32 in/out: out = clamp(silu(x@w1t) * (x@w3t), ±65504) @ w2t
// x[8192,3072], w13[16384,3072] (rows 0..8191 = w3 -> x3, 8192.. = w1 -> x1), w2[3072,8192].
// bf16 compute via cvt pre-pass; mfma_f32_16x16x32_bf16; fp32 accum; fp32 out.
// Round-10: BK=32 everywhere -> smaller LDS buffers -> proven 1-barrier/counted-vmcnt/
//   depth-2 skeleton at BM=256 for gateup (3x32KB=96KB), and 2 blocks/CU for down
//   (3x24KB=72KB) for cross-block phase overlap. 16x16x32 frags; (row>>1)&3 slot
//   swizzle (4 slots) == proven bank occupancy of the BK=64 row&7 scheme.
// Swizzle rule #21: pre-swizzled global source + linear gload_lds dest + swizzled ds_read.

typedef __attribute__((ext_vector_type(8))) __bf16 bf16x8;
typedef __attribute__((ext_vector_type(4))) float f32x4;

#define GLD_LDS16(gptr, lptr)                                                        \
  __builtin_amdgcn_global_load_lds(                                                  \
      (const __attribute__((address_space(1))) void*)(gptr),                         \
      (__attribute__((address_space(3))) void*)(lptr), 16, 0, 0)

#define VMCNT(n) asm volatile("s_waitcnt vmcnt(" #n ")" ::: "memory")
#define BAR()    __builtin_amdgcn_s_barrier()

#define MFMA16(a, b, c) __builtin_amdgcn_mfma_f32_16x16x32_bf16((a), (b), (c), 0, 0, 0)

__device__ __forceinline__ __bf16 bfr(float f) {  // RNE fp32->bf16
  unsigned int u = __builtin_bit_cast(unsigned int, f);
  unsigned short r = (unsigned short)((u + 0x7FFFu + ((u >> 16) & 1u)) >> 16);
  return __builtin_bit_cast(__bf16, r);
}

// ---------------- fp32 -> bf16 conversion pre-pass ----------------
__global__ __launch_bounds__(256)
void k_cvt(const float* __restrict__ src, unsigned short* __restrict__ dst, long n) {
  long i = ((long)blockIdx.x * 256 + threadIdx.x) * 8;
  const long stride = (long)gridDim.x * 256 * 8;
  for (; i < n; i += stride) {
    float4 f0 = *(const float4*)(src + i);
    float4 f1 = *(const float4*)(src + i + 4);
    bf16x8 o;
    o[0] = bfr(f0.x); o[1] = bfr(f0.y); o[2] = bfr(f0.z); o[3] = bfr(f0.w);
    o[4] = bfr(f1.x); o[5] = bfr(f1.y); o[6] = bfr(f1.z); o[7] = bfr(f1.w);
    *(bf16x8*)(dst + i) = o;
  }
}

// ============ Kernel 1: fused gate/up, 256x128 g-tile, BK=32, 3-buf, 1 bar/K-tile ======
// 8 waves (2M x 4N); per-wave 128 rows x (32 B3 + 32 B1 cols). Per K-tile:
// VMCNT(4); BAR; 12 ds_read (8 A + 2 B3 + 2 B1); stage c+2 (4 gload_lds); prio; 32 MFMA.
__global__ __launch_bounds__(512, 2)
void k_gateup16(const unsigned short* __restrict__ X,
                const unsigned short* __restrict__ W13,
                __hip_bfloat16* __restrict__ G)
{
  constexpr int K = 3072, LDG = 8192, NT = K / 32;
  __shared__ unsigned short lds[49152];  // 96KB: 3 bufs x 16384 shorts
                                         // buf e @ e*16384: A[256][32]@0, B3[128][32]@8192, B1@12288

  const int t = threadIdx.x, l = t & 63, wid = t >> 6;
  const int wm = wid >> 2, wn = wid & 3;          // 2M x 4N
  const int l15 = l & 15, lhi = l >> 4;

  const int bid = blockIdx.x;                     // 2048 blocks, XCD-chunked (8*256)
  const int swz = (bid & 7) * 256 + (bid >> 3);
  const int mb = swz >> 6, nb = swz & 63;

  // staging: 64B rows, 4 lanes/row; srow 0..127; pre-swizzled source slot
  const int srow = t >> 2;
  const int scol = ((t & 3) ^ ((srow >> 1) & 3)) * 8;
  const unsigned short* xa = X   + (size_t)(mb * 256 + srow) * K + scol;
  const unsigned short* b3 = W13 + (size_t)(nb * 128 + srow) * K + scol;
  const unsigned short* b1 = W13 + (size_t)(8192 + nb * 128 + srow) * K + scol;
  const int lo = t * 8;

#define GSTG(e, kt) do {                                                       \
    GLD_LDS16(xa + (kt),                  lds + (e) * 16384 + lo);             \
    GLD_LDS16(xa + (size_t)128 * K + (kt), lds + (e) * 16384 + 4096 + lo);     \
    GLD_LDS16(b3 + (kt),                  lds + (e) * 16384 + 8192 + lo);      \
    GLD_LDS16(b1 + (kt),                  lds + (e) * 16384 + 12288 + lo);     \
  } while (0)

  f32x4 acc3[8][2], acc1[8][2];
#pragma unroll
  for (int m = 0; m < 8; ++m)
#pragma unroll
    for (int n = 0; n < 2; ++n) {
      acc3[m][n] = (f32x4){0.f, 0.f, 0.f, 0.f};
      acc1[m][n] = (f32x4){0.f, 0.f, 0.f, 0.f};
    }

  // prologue: tiles 0,1
  GSTG(0, 0);
  GSTG(1, 32);

  for (int c = 0; c < NT; ++c) {
    const int e = c % 3;
    const int eS = (c + 2) % 3;                    // buffer of tile c-1 (reads retired)
    const int k2 = (c + 2 < NT ? c + 2 : 0) * 32;  // wrap keeps load count uniform
    const int Ab = e * 16384, B3b = Ab + 8192, B1b = Ab + 12288;

    VMCNT(4);    // tile c's 4 landed (tile c+1's 4 in flight)
    BAR();

    bf16x8 ra[8], r3[2], r1[2];
#pragma unroll
    for (int mf = 0; mf < 8; ++mf) {
      const int row = wm * 128 + mf * 16 + l15;
      ra[mf] = *(const bf16x8*)(lds + Ab + row * 32 + ((lhi ^ ((row >> 1) & 3)) * 8));
    }
#pragma unroll
    for (int nf = 0; nf < 2; ++nf) {
      const int row = wn * 32 + nf * 16 + l15;
      const int sl = (lhi ^ ((row >> 1) & 3)) * 8;
      r3[nf] = *(const bf16x8*)(lds + B3b + row * 32 + sl);
      r1[nf] = *(const bf16x8*)(lds + B1b + row * 32 + sl);
    }

    // stage tile c+2 into buffer of tile c-1 (reads retired before this BAR)
    GSTG(eS, k2);

    __builtin_amdgcn_s_setprio(1);
#pragma unroll
    for (int mf = 0; mf < 8; ++mf)
#pragma unroll
      for (int nf = 0; nf < 2; ++nf) {
        acc3[mf][nf] = MFMA16(ra[mf], r3[nf], acc3[mf][nf]);
        acc1[mf][nf] = MFMA16(ra[mf], r1[nf], acc1[mf][nf]);
      }
    __builtin_amdgcn_s_setprio(0);
  }

  // epilogue: g = clamp(silu(x1)*x3). 16x16 C/D: col=l15, row=lhi*4+r
  const int gr0 = mb * 256 + wm * 128;
  const int gc0 = nb * 128 + wn * 32;
#pragma unroll
  for (int mf = 0; mf < 8; ++mf)
#pragma unroll
    for (int nf = 0; nf < 2; ++nf)
#pragma unroll
      for (int r = 0; r < 4; ++r) {
        float h3 = acc3[mf][nf][r];
        float h1 = acc1[mf][nf][r];
        float s  = h1 / (1.f + __expf(-h1));
        float g  = fminf(fmaxf(s * h3, -65504.f), 65504.f);
        G[(size_t)(gr0 + mf * 16 + lhi * 4 + r) * LDG + (gc0 + nf * 16 + l15)] =
            __float2bfloat16(g);
      }
#undef GSTG
}

// ============ Kernel 2: down proj, 256x128 tile, BK=32, 3-buf, 2 blocks/CU ============
// 8 waves (4M x 2N), per-wave 64x64. Per K-tile: VMCNT(3); BAR; 8 ds_read;
// stage c+2 (3 gload_lds); prio; 16 MFMA. 72KB LDS -> 2 blocks/CU overlap.
__global__ __launch_bounds__(512, 2)
void k_down12(const unsigned short* __restrict__ Gm,
              const unsigned short* __restrict__ W2,
              float* __restrict__ Out)
{
  constexpr int K = 8192, LDO = 3072, NT = K / 32;
  __shared__ unsigned short lds[36864];  // 72KB: 3 bufs x 12288 shorts
                                         // buf e @ e*12288: A[256][32]@0, B[128][32]@8192

  const int t = threadIdx.x, l = t & 63, wid = t >> 6;
  const int wm = wid >> 1, wn = wid & 1;          // 4M x 2N
  const int l15 = l & 15, lhi = l >> 4;

  const int bid = blockIdx.x;                     // 768 blocks
  const int swz = (bid & 7) * 96 + (bid >> 3);
  const int mb = swz / 24, nb = swz % 24;

  const int srow = t >> 2;                        // 0..127, 4 lanes/row
  const int scol = ((t & 3) ^ ((srow >> 1) & 3)) * 8;
  const unsigned short* ga = Gm + (size_t)(mb * 256 + srow) * K + scol;
  const unsigned short* wb = W2 + (size_t)(nb * 128 + srow) * K + scol;
  const int lo = t * 8;

#define DSTG(e, kt) do {                                                       \
    GLD_LDS16(ga + (kt),                  lds + (e) * 12288 + lo);             \
    GLD_LDS16(ga + (size_t)128 * K + (kt), lds + (e) * 12288 + 4096 + lo);     \
    GLD_LDS16(wb + (kt),                  lds + (e) * 12288 + 8192 + lo);      \
  } while (0)

  f32x4 acc[4][4];
#pragma unroll
  for (int mf = 0; mf < 4; ++mf)
#pragma unroll
    for (int nf = 0; nf < 4; ++nf)
      acc[mf][nf] = (f32x4){0.f, 0.f, 0.f, 0.f};

  // prologue: tiles 0,1
  DSTG(0, 0);
  DSTG(1, 32);

  for (int c = 0; c < NT; ++c) {
    const int e = c % 3;
    const int eS = (c + 2) % 3;
    const int k2 = (c + 2 < NT ? c + 2 : 0) * 32;
    const int Ab = e * 12288, Bb = Ab + 8192;

    VMCNT(3);    // tile c's 3 landed (tile c+1's 3 in flight)
    BAR();

    bf16x8 ra[4], rb[4];
#pragma unroll
    for (int mf = 0; mf < 4; ++mf) {
      const int row = wm * 64 + mf * 16 + l15;
      ra[mf] = *(const bf16x8*)(lds + Ab + row * 32 + ((lhi ^ ((row >> 1) & 3)) * 8));
    }
#pragma unroll
    for (int nf = 0; nf < 4; ++nf) {
      const int row = wn * 64 + nf * 16 + l15;
      rb[nf] = *(const bf16x8*)(lds + Bb + row * 32 + ((lhi ^ ((row >> 1) & 3)) * 8));
    }

    // stage tile c+2 into buffer of tile c-1
    DSTG(eS, k2);

    __builtin_amdgcn_s_setprio(1);
#pragma unroll
    for (int mf = 0; mf < 4; ++mf)
#pragma unroll
      for (int nf = 0; nf < 4; ++nf)
        acc[mf][nf] = MFMA16(ra[mf], rb[nf], acc[mf][nf]);
    __builtin_amdgcn_s_setprio(0);
  }

  const int r0 = mb * 256 + wm * 64;
  const int c0 = nb * 128 + wn * 64;
#pragma unroll
  for (int mf = 0; mf < 4; ++mf)
#pragma unroll
    for (int nf = 0; nf < 4; ++nf)
#pragma unroll
      for (int r = 0; r < 4; ++r)
        Out[(size_t)(r0 + mf * 16 + lhi * 4 + r) * LDO + (c0 + nf * 16 + l15)] =
            acc[mf][nf][r];
#undef DSTG
}

extern "C" void kernel_launch(void* const* d_in, const int* in_sizes, int n_in,
                              void* d_out, int out_size, void* d_ws, size_t ws_size,
                              hipStream_t stream) {
  const float* x   = (const float*)d_in[0];   // [2,4096,3072] f32
  const float* w13 = (const float*)d_in[1];   // [16384,3072] f32
  const float* w2  = (const float*)d_in[2];   // [3072,8192] f32
  float* out = (float*)d_out;                 // [2,4096,3072] f32

  const long NX = 25165824L, NW13 = 50331648L, NW2 = 25165824L;
  const size_t XB = 50331648, W13B = 100663296, W2B = 50331648;

  unsigned short* xb   = (unsigned short*)d_ws;
  unsigned short* w13b = (unsigned short*)((char*)d_ws + XB);
  unsigned short* w2b  = (unsigned short*)((char*)d_ws + XB + W13B);
  __hip_bfloat16* g    = (__hip_bfloat16*)((char*)d_ws + XB + W13B + W2B);

  k_cvt<<<2048, 256, 0, stream>>>(x,   xb,   NX);
  k_cvt<<<2048, 256, 0, stream>>>(w13, w13b, NW13);
  k_cvt<<<2048, 256, 0, stream>>>(w2,  w2b,  NW2);
  k_gateup16<<<2048, 512, 0, stream>>>(xb, w13b, g);
  k_down12<<<768, 512, 0, stream>>>((const unsigned short*)g, w2b, out);
}

// Round 12
// 1214.842 us; speedup vs baseline: 1.8106x; 1.0399x over previous
//
#include <hip/hip_runtime.h>
#include <hip/hip_bf16.h>

// SwiGLU FFN, fp32 in/out: out = clamp(silu(x@w1t) * (x@w3t), ±65504) @ w2t
// x[8192,3072], w13[16384,3072] (rows 0..8191 = w3 -> x3, 8192.. = w1 -> x1), w2[3072,8192].
// bf16 compute via cvt pre-pass; mfma_f32_16x16x32_bf16; fp32 accum; fp32 out.
// Round-12: R11's single-barrier 160KB pipeline with the PROVEN 2Mx4N wave map
//   (R11 failed because 4Mx2N + nf<2 left half the g-columns unwritten — coverage bug,
//   not a pipeline bug). Per-wave 128 rows x 32 cols, acc3[8][2] + acc1[8][2].
//   LDS: A[2]x32KB (stage c+1) + B3[3]x16KB + B1[3]x16KB (stage c+2) = 160KB.
//   Per K-tile: VMCNT(4) (retires A(c)+B(c), keeps B(c+1)); BAR; 24 ds_read;
//   STA(c+1); STB(c+2); prio1; 32 MFMA; prio0.  One barrier per tile.
// Down = R6/R7-proven down11 (67% MfmaUtil), unchanged.
// 16x16x32 frags + row&7 slot swizzle (0 conflicts). Rule #21 both-sides swizzle.

typedef __attribute__((ext_vector_type(8))) __bf16 bf16x8;
typedef __attribute__((ext_vector_type(4))) float f32x4;

#define GLD_LDS16(gptr, lptr)                                                        \
  __builtin_amdgcn_global_load_lds(                                                  \
      (const __attribute__((address_space(1))) void*)(gptr),                         \
      (__attribute__((address_space(3))) void*)(lptr), 16, 0, 0)

#define VMCNT(n) asm volatile("s_waitcnt vmcnt(" #n ")" ::: "memory")
#define BAR()    __builtin_amdgcn_s_barrier()

#define MFMA16(a, b, c) __builtin_amdgcn_mfma_f32_16x16x32_bf16((a), (b), (c), 0, 0, 0)

__device__ __forceinline__ __bf16 bfr(float f) {  // RNE fp32->bf16
  unsigned int u = __builtin_bit_cast(unsigned int, f);
  unsigned short r = (unsigned short)((u + 0x7FFFu + ((u >> 16) & 1u)) >> 16);
  return __builtin_bit_cast(__bf16, r);
}

// ---------------- fp32 -> bf16 conversion pre-pass ----------------
__global__ __launch_bounds__(256)
void k_cvt(const float* __restrict__ src, unsigned short* __restrict__ dst, long n) {
  long i = ((long)blockIdx.x * 256 + threadIdx.x) * 8;
  const long stride = (long)gridDim.x * 256 * 8;
  for (; i < n; i += stride) {
    float4 f0 = *(const float4*)(src + i);
    float4 f1 = *(const float4*)(src + i + 4);
    bf16x8 o;
    o[0] = bfr(f0.x); o[1] = bfr(f0.y); o[2] = bfr(f0.z); o[3] = bfr(f0.w);
    o[4] = bfr(f1.x); o[5] = bfr(f1.y); o[6] = bfr(f1.z); o[7] = bfr(f1.w);
    *(bf16x8*)(dst + i) = o;
  }
}

// ============ Kernel 1: fused gate/up, 256x128 g-tile, BK=64, A dbuf + B 3-buf ==========
// 8 waves (2M x 4N); per-wave 128 A-rows x 32 g-cols (B3 and B1).
__global__ __launch_bounds__(512, 2)
void k_gateup18(const unsigned short* __restrict__ X,
                const unsigned short* __restrict__ W13,
                __hip_bfloat16* __restrict__ G)
{
  constexpr int K = 3072, LDG = 8192, NT = K / 64;
  __shared__ unsigned short lds[81920];  // 160KB exactly:
                                         // A[2] @ 0,16384 (32KB each)
                                         // B3[3] @ 32768 + e*8192 (16KB each)
                                         // B1[3] @ 57344 + e*8192 (16KB each)

  const int t = threadIdx.x, l = t & 63, wid = t >> 6;
  const int wm = wid >> 2, wn = wid & 3;          // 2M x 4N  (PROVEN coverage)
  const int l15 = l & 15, lhi = l >> 4, sw = l15 & 7;

  const int bid = blockIdx.x;                     // 2048 blocks, XCD-chunked (8*256)
  const int swz = (bid & 7) * 256 + (bid >> 3);
  const int mb = swz >> 6, nb = swz & 63;         // mb 0..31, nb 0..63

  // staging: 128B rows, 8 lanes/row; srow 0..63; pre-swizzled source slot
  const int srow = t >> 3;
  const int scol = ((t & 7) ^ (srow & 7)) * 8;
  const unsigned short* xa = X   + (size_t)(mb * 256 + srow) * K + scol;
  const unsigned short* b3 = W13 + (size_t)(nb * 128 + srow) * K + scol;
  const unsigned short* b1 = W13 + (size_t)(8192 + nb * 128 + srow) * K + scol;
  const int lo = t * 8;

#define STA(d, kt) do {                                                        \
    GLD_LDS16(xa + (kt),                  lds + (d) * 16384 + lo);             \
    GLD_LDS16(xa + (size_t)64 * K + (kt),  lds + (d) * 16384 + 4096 + lo);     \
    GLD_LDS16(xa + (size_t)128 * K + (kt), lds + (d) * 16384 + 8192 + lo);     \
    GLD_LDS16(xa + (size_t)192 * K + (kt), lds + (d) * 16384 + 12288 + lo);    \
  } while (0)
#define STB(e, kt) do {                                                        \
    GLD_LDS16(b3 + (kt),                 lds + 32768 + (e) * 8192 + lo);       \
    GLD_LDS16(b3 + (size_t)64 * K + (kt), lds + 32768 + (e) * 8192 + 4096 + lo); \
    GLD_LDS16(b1 + (kt),                 lds + 57344 + (e) * 8192 + lo);       \
    GLD_LDS16(b1 + (size_t)64 * K + (kt), lds + 57344 + (e) * 8192 + 4096 + lo); \
  } while (0)

  f32x4 acc3[8][2], acc1[8][2];
#pragma unroll
  for (int m = 0; m < 8; ++m)
#pragma unroll
    for (int n = 0; n < 2; ++n) {
      acc3[m][n] = (f32x4){0.f, 0.f, 0.f, 0.f};
      acc1[m][n] = (f32x4){0.f, 0.f, 0.f, 0.f};
    }

  // prologue (issue order = steady state): B(0); A(0); B(1)
  STB(0, 0);
  STA(0, 0);
  STB(1, 64);

  for (int c = 0; c < NT; ++c) {
    const int d = c & 1, dn = d ^ 1;               // A dbuf
    const int e = c % 3;                           // B 3-buf
    const int eS = (c + 2) % 3;
    const int k1 = (c + 1 < NT ? c + 1 : 0) * 64;
    const int k2 = (c + 2 < NT ? c + 2 : c + 2 - NT) * 64;
    const int Ab = d * 16384, B3b = 32768 + e * 8192, B1b = 57344 + e * 8192;

    // entry: retire B(c) [issued iter c-2] and A(c) [issued iter c-1];
    // keep B(c+1)'s 4 in flight (FIFO decrement, m135)
    VMCNT(4);
    BAR();

    bf16x8 ra[8][2], r3[2][2], r1[2][2];
#pragma unroll
    for (int mf = 0; mf < 8; ++mf)
#pragma unroll
      for (int kk = 0; kk < 2; ++kk) {
        const int row = wm * 128 + mf * 16 + l15;
        ra[mf][kk] = *(const bf16x8*)(lds + Ab + row * 64 + ((kk * 4 + lhi) ^ sw) * 8);
      }
#pragma unroll
    for (int nf = 0; nf < 2; ++nf)
#pragma unroll
      for (int kk = 0; kk < 2; ++kk) {
        const int row = wn * 32 + nf * 16 + l15;
        const int sl = ((kk * 4 + lhi) ^ sw) * 8;
        r3[nf][kk] = *(const bf16x8*)(lds + B3b + row * 64 + sl);
        r1[nf][kk] = *(const bf16x8*)(lds + B1b + row * 64 + sl);
      }

    // stage A(c+1) into the other A buf (its previous content A(c-1) was read in
    // iter c-1; all waves' reads retired before they reached this iter's barrier).
    // Then B(c+2) into the B buf of tile c-1. A first, B last (vmcnt algebra).
    STA(dn, k1);
    STB(eS, k2);

    __builtin_amdgcn_s_setprio(1);
#pragma unroll
    for (int mf = 0; mf < 8; ++mf)
#pragma unroll
      for (int nf = 0; nf < 2; ++nf)
#pragma unroll
        for (int kk = 0; kk < 2; ++kk) {
          acc3[mf][nf] = MFMA16(ra[mf][kk], r3[nf][kk], acc3[mf][nf]);
          acc1[mf][nf] = MFMA16(ra[mf][kk], r1[nf][kk], acc1[mf][nf]);
        }
    __builtin_amdgcn_s_setprio(0);
  }

  // epilogue: g = clamp(silu(x1)*x3). 16x16 C/D: col=l15, row=lhi*4+r
  const int gr0 = mb * 256 + wm * 128;
  const int gc0 = nb * 128 + wn * 32;
#pragma unroll
  for (int mf = 0; mf < 8; ++mf)
#pragma unroll
    for (int nf = 0; nf < 2; ++nf)
#pragma unroll
      for (int r = 0; r < 4; ++r) {
        float h3 = acc3[mf][nf][r];
        float h1 = acc1[mf][nf][r];
        float s  = h1 / (1.f + __expf(-h1));
        float g  = fminf(fmaxf(s * h3, -65504.f), 65504.f);
        G[(size_t)(gr0 + mf * 16 + lhi * 4 + r) * LDG + (gc0 + nf * 16 + l15)] =
            __float2bfloat16(g);
      }
#undef STA
#undef STB
}

// ============ Kernel 2: down proj, 256x128 tile, BK=64, 3-buf, 1 phase/K-tile ============
// 8 waves (4M x 2N), per-wave 64x64, 16x16x32 frags. Proven 67% MfmaUtil — unchanged.
__global__ __launch_bounds__(512, 2)
void k_down11(const unsigned short* __restrict__ Gm,
              const unsigned short* __restrict__ W2,
              float* __restrict__ Out)
{
  constexpr int K = 8192, LDO = 3072, NT = K / 64;
  __shared__ unsigned short lds[73728];  // 144KB: A[3]@0 (16384 ea) | B[3]@49152 (8192 ea)

  const int t = threadIdx.x, l = t & 63, wid = t >> 6;
  const int wm = wid >> 1, wn = wid & 1;          // 4M x 2N
  const int l15 = l & 15, lhi = l >> 4, sw = l15 & 7;

  const int bid = blockIdx.x;                     // 768 blocks
  const int swz = (bid & 7) * 96 + (bid >> 3);
  const int mb = swz / 24, nb = swz % 24;

  const int srow = t >> 3;
  const int scol = ((t & 7) ^ (srow & 7)) * 8;
  const unsigned short* ga = Gm + (size_t)(mb * 256 + srow) * K + scol;
  const unsigned short* wb = W2 + (size_t)(nb * 128 + srow) * K + scol;
  const int lo = t * 8;

#define DST_A(e, kt) do {                                                       \
    GLD_LDS16(ga + (kt),                 lds + (e) * 16384 + lo);               \
    GLD_LDS16(ga + (size_t)64 * K + (kt),  lds + (e) * 16384 + 4096 + lo);      \
    GLD_LDS16(ga + (size_t)128 * K + (kt), lds + (e) * 16384 + 8192 + lo);      \
    GLD_LDS16(ga + (size_t)192 * K + (kt), lds + (e) * 16384 + 12288 + lo);     \
  } while (0)
#define DST_B(e, kt) do {                                                       \
    GLD_LDS16(wb + (kt),                lds + 49152 + (e) * 8192 + lo);         \
    GLD_LDS16(wb + (size_t)64 * K + (kt), lds + 49152 + (e) * 8192 + 4096 + lo); \
  } while (0)

  f32x4 acc[4][4];
#pragma unroll
  for (int mf = 0; mf < 4; ++mf)
#pragma unroll
    for (int nf = 0; nf < 4; ++nf)
      acc[mf][nf] = (f32x4){0.f, 0.f, 0.f, 0.f};

  // prologue: tiles 0,1 (6 loads each)
  DST_B(0, 0);  DST_A(0, 0);
  DST_B(1, 64); DST_A(1, 64);

  for (int c = 0; c < NT; ++c) {
    const int e = c % 3;
    const int eS = (c + 2) % 3;
    const int k2 = (c + 2 < NT ? c + 2 : 0) * 64;

    VMCNT(6);    // tile c's 6 landed (tile c+1's 6 in flight)
    BAR();

    bf16x8 ra[4][2], rb[4][2];
#pragma unroll
    for (int mf = 0; mf < 4; ++mf)
#pragma unroll
      for (int kk = 0; kk < 2; ++kk)
        ra[mf][kk] = *(const bf16x8*)(lds + e * 16384 + (wm * 64 + mf * 16 + l15) * 64 + ((kk * 4 + lhi) ^ sw) * 8);
#pragma unroll
    for (int nf = 0; nf < 4; ++nf)
#pragma unroll
      for (int kk = 0; kk < 2; ++kk)
        rb[nf][kk] = *(const bf16x8*)(lds + 49152 + e * 8192 + (wn * 64 + nf * 16 + l15) * 64 + ((kk * 4 + lhi) ^ sw) * 8);

    // stage tile c+2 into buffer of tile c-1 (reads done before this iter's barrier)
    DST_B(eS, k2);
    DST_A(eS, k2);

    __builtin_amdgcn_s_setprio(1);
#pragma unroll
    for (int mf = 0; mf < 4; ++mf)
#pragma unroll
      for (int nf = 0; nf < 4; ++nf)
#pragma unroll
        for (int kk = 0; kk < 2; ++kk)
          acc[mf][nf] = MFMA16(ra[mf][kk], rb[nf][kk], acc[mf][nf]);
    __builtin_amdgcn_s_setprio(0);
  }

  const int r0 = mb * 256 + wm * 64;
  const int c0 = nb * 128 + wn * 64;
#pragma unroll
  for (int mf = 0; mf < 4; ++mf)
#pragma unroll
    for (int nf = 0; nf < 4; ++nf)
#pragma unroll
      for (int r = 0; r < 4; ++r)
        Out[(size_t)(r0 + mf * 16 + lhi * 4 + r) * LDO + (c0 + nf * 16 + l15)] =
            acc[mf][nf][r];
#undef DST_A
#undef DST_B
}

extern "C" void kernel_launch(void* const* d_in, const int* in_sizes, int n_in,
                              void* d_out, int out_size, void* d_ws, size_t ws_size,
                              hipStream_t stream) {
  const float* x   = (const float*)d_in[0];   // [2,4096,3072] f32
  const float* w13 = (const float*)d_in[1];   // [16384,3072] f32
  const float* w2  = (const float*)d_in[2];   // [3072,8192] f32
  float* out = (float*)d_out;                 // [2,4096,3072] f32

  const long NX = 25165824L, NW13 = 50331648L, NW2 = 25165824L;
  const size_t XB = 50331648, W13B = 100663296, W2B = 50331648;

  unsigned short* xb   = (unsigned short*)d_ws;
  unsigned short* w13b = (unsigned short*)((char*)d_ws + XB);
  unsigned short* w2b  = (unsigned short*)((char*)d_ws + XB + W13B);
  __hip_bfloat16* g    = (__hip_bfloat16*)((char*)d_ws + XB + W13B + W2B);

  k_cvt<<<2048, 256, 0, stream>>>(x,   xb,   NX);
  k_cvt<<<2048, 256, 0, stream>>>(w13, w13b, NW13);
  k_cvt<<<2048, 256, 0, stream>>>(w2,  w2b,  NW2);
  k_gateup18<<<2048, 512, 0, stream>>>(xb, w13b, g);
  k_down11<<<768, 512, 0, stream>>>((const unsigned short*)g, w2b, out);
}

// Round 13
// 1168.653 us; speedup vs baseline: 1.8821x; 1.0395x over previous
//
#include <hip/hip_runtime.h>
#include <hip/hip_bf16.h>

// SwiGLU FFN, fp32 in/out: out = clamp(silu(x@w1t) * (x@w3t), ±65504) @ w2t
// x[8192,3072], w13[16384,3072] (rows 0..8191 = w3 -> x3, 8192.. = w1 -> x1), w2[3072,8192].
// bf16 compute via cvt pre-pass; mfma_f32_16x16x32_bf16; fp32 accum; fp32 out.
// Round-13: best-known config (R7) + low-risk tweaks:
//   gateup = R7 2-phase B-split skeleton (58.5%) with (a) A-read stagger in ph1
//   (12 reads -> 16 MFMA -> 8 reads -> 16 MFMA), (b) staging issued right after BAR.
//   down = proven down11 (67%). cvt = single fused kernel (3 segments).
// 16x16x32 frags + row&7 slot swizzle (0 conflicts). Rule #21 both-sides swizzle.

typedef __attribute__((ext_vector_type(8))) __bf16 bf16x8;
typedef __attribute__((ext_vector_type(4))) float f32x4;

#define GLD_LDS16(gptr, lptr)                                                        \
  __builtin_amdgcn_global_load_lds(                                                  \
      (const __attribute__((address_space(1))) void*)(gptr),                         \
      (__attribute__((address_space(3))) void*)(lptr), 16, 0, 0)

#define VMCNT(n) asm volatile("s_waitcnt vmcnt(" #n ")" ::: "memory")
#define BAR()    __builtin_amdgcn_s_barrier()

#define MFMA16(a, b, c) __builtin_amdgcn_mfma_f32_16x16x32_bf16((a), (b), (c), 0, 0, 0)

__device__ __forceinline__ __bf16 bfr(float f) {  // RNE fp32->bf16
  unsigned int u = __builtin_bit_cast(unsigned int, f);
  unsigned short r = (unsigned short)((u + 0x7FFFu + ((u >> 16) & 1u)) >> 16);
  return __builtin_bit_cast(__bf16, r);
}

// ---------------- fused fp32 -> bf16 conversion (x, w13, w2 in one launch) -------------
__global__ __launch_bounds__(256)
void k_cvt3(const float* __restrict__ s0, const float* __restrict__ s1,
            const float* __restrict__ s2, unsigned short* __restrict__ d0,
            unsigned short* __restrict__ d1, unsigned short* __restrict__ d2) {
  const long N0 = 25165824L, N1 = 50331648L, N2 = 25165824L;
  const long NTOT = N0 + N1 + N2;
  long i = ((long)blockIdx.x * 256 + threadIdx.x) * 8;
  const long stride = (long)gridDim.x * 256 * 8;
  for (; i < NTOT; i += stride) {
    const float* s; unsigned short* d; long j = i;
    if (j < N0)            { s = s0; d = d0; }
    else if (j < N0 + N1)  { s = s1; d = d1; j -= N0; }
    else                   { s = s2; d = d2; j -= N0 + N1; }
    float4 f0 = *(const float4*)(s + j);
    float4 f1 = *(const float4*)(s + j + 4);
    bf16x8 o;
    o[0] = bfr(f0.x); o[1] = bfr(f0.y); o[2] = bfr(f0.z); o[3] = bfr(f0.w);
    o[4] = bfr(f1.x); o[5] = bfr(f1.y); o[6] = bfr(f1.z); o[7] = bfr(f1.w);
    *(bf16x8*)(d + j) = o;
  }
}

// ============ Kernel 1: fused gate/up, 256x128 g-tile, BK=64, 2-buf, 2-phase ============
// 8 waves (2M x 4N), per-wave 128 rows x (32 B3-cols + 32 B1-cols). 16x16x32 frags.
// PH1: VMCNT(2); BAR; stage A(c+1)+B3(c+1); rd ra[0..3]+B3; 16 MFMA acc3;
//      rd ra[4..7]; 16 MFMA acc3.
// PH2: VMCNT(6); BAR; stage B1(c+1); rd B1; 32 MFMA acc1 (reuses ra).
__global__ __launch_bounds__(512, 2)
void k_gateup19(const unsigned short* __restrict__ X,
                const unsigned short* __restrict__ W13,
                __hip_bfloat16* __restrict__ G)
{
  constexpr int K = 3072, LDG = 8192, NT = K / 64;
  __shared__ unsigned short lds[65536];  // 128KB: 2 bufs x (A[256][64] | B3[128][64] | B1[128][64])

  const int t = threadIdx.x, l = t & 63, wid = t >> 6;
  const int wm = wid >> 2, wn = wid & 3;          // 2M x 4N
  const int l15 = l & 15, lhi = l >> 4, sw = l15 & 7;

  const int bid = blockIdx.x;                     // 2048 blocks, XCD-chunked
  const int swz = (bid & 7) * 256 + (bid >> 3);
  const int mb = swz >> 6, nb = swz & 63;

  const int srow = t >> 3;                        // 0..63
  const int scol = ((t & 7) ^ (srow & 7)) * 8;    // pre-swizzled global slot
  const unsigned short* xa = X   + (size_t)(mb * 256 + srow) * K + scol;
  const unsigned short* b3 = W13 + (size_t)(nb * 128 + srow) * K + scol;
  const unsigned short* b1 = W13 + (size_t)(8192 + nb * 128 + srow) * K + scol;
  const int lo = t * 8;

#define STG_A(d, kt) do {                                                      \
    GLD_LDS16(xa + (kt),                  lds + (d) * 32768 + lo);             \
    GLD_LDS16(xa + (size_t)64 * K + (kt),  lds + (d) * 32768 + 4096 + lo);     \
    GLD_LDS16(xa + (size_t)128 * K + (kt), lds + (d) * 32768 + 8192 + lo);     \
    GLD_LDS16(xa + (size_t)192 * K + (kt), lds + (d) * 32768 + 12288 + lo);    \
  } while (0)
#define STG_B3(d, kt) do {                                                     \
    GLD_LDS16(b3 + (kt),                 lds + (d) * 32768 + 16384 + lo);      \
    GLD_LDS16(b3 + (size_t)64 * K + (kt), lds + (d) * 32768 + 20480 + lo);     \
  } while (0)
#define STG_B1(d, kt) do {                                                     \
    GLD_LDS16(b1 + (kt),                 lds + (d) * 32768 + 24576 + lo);      \
    GLD_LDS16(b1 + (size_t)64 * K + (kt), lds + (d) * 32768 + 28672 + lo);     \
  } while (0)

  f32x4 acc3[8][2], acc1[8][2];
#pragma unroll
  for (int m = 0; m < 8; ++m)
#pragma unroll
    for (int n = 0; n < 2; ++n) {
      acc3[m][n] = (f32x4){0.f, 0.f, 0.f, 0.f};
      acc1[m][n] = (f32x4){0.f, 0.f, 0.f, 0.f};
    }

  // prologue: stage tile 0 in steady-state order [A, B3 | B1]
  STG_A(0, 0); STG_B3(0, 0); STG_B1(0, 0);

  for (int c = 0; c < NT; ++c) {
    const int R = c & 1, S = R ^ 1;
    const int kn = (c + 1 < NT ? c + 1 : 0) * 64;   // wrap keeps load count uniform
    const int Ab = R * 32768, B3b = Ab + 16384, B1b = Ab + 24576;

    // ---- PH1: A + B3 ----
    VMCNT(2);                      // A(c)+B3(c) landed; B1(c) still in flight
    BAR();                         // all waves' A/B3 landed
    STG_A(S, kn); STG_B3(S, kn);   // issue next-tile loads FIRST (max latency cover)

    bf16x8 ra[8][2], r3[2][2];
#pragma unroll
    for (int mf = 0; mf < 4; ++mf)
#pragma unroll
      for (int kk = 0; kk < 2; ++kk) {
        const int row = wm * 128 + mf * 16 + l15;
        ra[mf][kk] = *(const bf16x8*)(lds + Ab + row * 64 + ((kk * 4 + lhi) ^ sw) * 8);
      }
#pragma unroll
    for (int nf = 0; nf < 2; ++nf)
#pragma unroll
      for (int kk = 0; kk < 2; ++kk) {
        const int row = wn * 32 + nf * 16 + l15;
        r3[nf][kk] = *(const bf16x8*)(lds + B3b + row * 64 + ((kk * 4 + lhi) ^ sw) * 8);
      }
    __builtin_amdgcn_s_setprio(1);
#pragma unroll
    for (int mf = 0; mf < 4; ++mf)
#pragma unroll
      for (int nf = 0; nf < 2; ++nf)
#pragma unroll
        for (int kk = 0; kk < 2; ++kk)
          acc3[mf][nf] = MFMA16(ra[mf][kk], r3[nf][kk], acc3[mf][nf]);
    __builtin_amdgcn_s_setprio(0);
    // second half of A reads hides under the first half's MFMAs
#pragma unroll
    for (int mf = 4; mf < 8; ++mf)
#pragma unroll
      for (int kk = 0; kk < 2; ++kk) {
        const int row = wm * 128 + mf * 16 + l15;
        ra[mf][kk] = *(const bf16x8*)(lds + Ab + row * 64 + ((kk * 4 + lhi) ^ sw) * 8);
      }
    __builtin_amdgcn_s_setprio(1);
#pragma unroll
    for (int mf = 4; mf < 8; ++mf)
#pragma unroll
      for (int nf = 0; nf < 2; ++nf)
#pragma unroll
        for (int kk = 0; kk < 2; ++kk)
          acc3[mf][nf] = MFMA16(ra[mf][kk], r3[nf][kk], acc3[mf][nf]);
    __builtin_amdgcn_s_setprio(0);

    // ---- PH2: B1 (A-frags reused) ----
    VMCNT(6);                      // B1(c) landed; A/B3(c+1)'s 6 in flight
    BAR();
    STG_B1(S, kn);                 // 2 loads, issued first
    bf16x8 r1[2][2];
#pragma unroll
    for (int nf = 0; nf < 2; ++nf)
#pragma unroll
      for (int kk = 0; kk < 2; ++kk) {
        const int row = wn * 32 + nf * 16 + l15;
        r1[nf][kk] = *(const bf16x8*)(lds + B1b + row * 64 + ((kk * 4 + lhi) ^ sw) * 8);
      }
    __builtin_amdgcn_s_setprio(1);
#pragma unroll
    for (int mf = 0; mf < 8; ++mf)
#pragma unroll
      for (int nf = 0; nf < 2; ++nf)
#pragma unroll
        for (int kk = 0; kk < 2; ++kk)
          acc1[mf][nf] = MFMA16(ra[mf][kk], r1[nf][kk], acc1[mf][nf]);
    __builtin_amdgcn_s_setprio(0);
  }

  // epilogue: g = clamp(silu(x1)*x3). 16x16 C/D: col=l15, row=lhi*4+r
  const int gr0 = mb * 256 + wm * 128;
  const int gc0 = nb * 128 + wn * 32;
#pragma unroll
  for (int mf = 0; mf < 8; ++mf)
#pragma unroll
    for (int nf = 0; nf < 2; ++nf)
#pragma unroll
      for (int r = 0; r < 4; ++r) {
        float h3 = acc3[mf][nf][r];
        float h1 = acc1[mf][nf][r];
        float s  = h1 / (1.f + __expf(-h1));
        float g  = fminf(fmaxf(s * h3, -65504.f), 65504.f);
        G[(size_t)(gr0 + mf * 16 + lhi * 4 + r) * LDG + (gc0 + nf * 16 + l15)] =
            __float2bfloat16(g);
      }
#undef STG_A
#undef STG_B3
#undef STG_B1
}

// ============ Kernel 2: down proj, 256x128 tile, BK=64, 3-buf, 1 phase/K-tile ============
// 8 waves (4M x 2N), per-wave 64x64, 16x16x32 frags. Proven 67% MfmaUtil — unchanged.
__global__ __launch_bounds__(512, 2)
void k_down11(const unsigned short* __restrict__ Gm,
              const unsigned short* __restrict__ W2,
              float* __restrict__ Out)
{
  constexpr int K = 8192, LDO = 3072, NT = K / 64;
  __shared__ unsigned short lds[73728];  // 144KB: A[3]@0 (16384 ea) | B[3]@49152 (8192 ea)

  const int t = threadIdx.x, l = t & 63, wid = t >> 6;
  const int wm = wid >> 1, wn = wid & 1;          // 4M x 2N
  const int l15 = l & 15, lhi = l >> 4, sw = l15 & 7;

  const int bid = blockIdx.x;                     // 768 blocks
  const int swz = (bid & 7) * 96 + (bid >> 3);
  const int mb = swz / 24, nb = swz % 24;

  const int srow = t >> 3;
  const int scol = ((t & 7) ^ (srow & 7)) * 8;
  const unsigned short* ga = Gm + (size_t)(mb * 256 + srow) * K + scol;
  const unsigned short* wb = W2 + (size_t)(nb * 128 + srow) * K + scol;
  const int lo = t * 8;

#define DST_A(e, kt) do {                                                       \
    GLD_LDS16(ga + (kt),                 lds + (e) * 16384 + lo);               \
    GLD_LDS16(ga + (size_t)64 * K + (kt),  lds + (e) * 16384 + 4096 + lo);      \
    GLD_LDS16(ga + (size_t)128 * K + (kt), lds + (e) * 16384 + 8192 + lo);      \
    GLD_LDS16(ga + (size_t)192 * K + (kt), lds + (e) * 16384 + 12288 + lo);     \
  } while (0)
#define DST_B(e, kt) do {                                                       \
    GLD_LDS16(wb + (kt),                lds + 49152 + (e) * 8192 + lo);         \
    GLD_LDS16(wb + (size_t)64 * K + (kt), lds + 49152 + (e) * 8192 + 4096 + lo); \
  } while (0)

  f32x4 acc[4][4];
#pragma unroll
  for (int mf = 0; mf < 4; ++mf)
#pragma unroll
    for (int nf = 0; nf < 4; ++nf)
      acc[mf][nf] = (f32x4){0.f, 0.f, 0.f, 0.f};

  // prologue: tiles 0,1 (6 loads each)
  DST_B(0, 0);  DST_A(0, 0);
  DST_B(1, 64); DST_A(1, 64);

  for (int c = 0; c < NT; ++c) {
    const int e = c % 3;
    const int eS = (c + 2) % 3;
    const int k2 = (c + 2 < NT ? c + 2 : 0) * 64;

    VMCNT(6);    // tile c's 6 landed (tile c+1's 6 in flight)
    BAR();

    bf16x8 ra[4][2], rb[4][2];
#pragma unroll
    for (int mf = 0; mf < 4; ++mf)
#pragma unroll
      for (int kk = 0; kk < 2; ++kk)
        ra[mf][kk] = *(const bf16x8*)(lds + e * 16384 + (wm * 64 + mf * 16 + l15) * 64 + ((kk * 4 + lhi) ^ sw) * 8);
#pragma unroll
    for (int nf = 0; nf < 4; ++nf)
#pragma unroll
      for (int kk = 0; kk < 2; ++kk)
        rb[nf][kk] = *(const bf16x8*)(lds + 49152 + e * 8192 + (wn * 64 + nf * 16 + l15) * 64 + ((kk * 4 + lhi) ^ sw) * 8);

    // stage tile c+2 into buffer of tile c-1 (reads done before this iter's barrier)
    DST_B(eS, k2);
    DST_A(eS, k2);

    __builtin_amdgcn_s_setprio(1);
#pragma unroll
    for (int mf = 0; mf < 4; ++mf)
#pragma unroll
      for (int nf = 0; nf < 4; ++nf)
#pragma unroll
        for (int kk = 0; kk < 2; ++kk)
          acc[mf][nf] = MFMA16(ra[mf][kk], rb[nf][kk], acc[mf][nf]);
    __builtin_amdgcn_s_setprio(0);
  }

  const int r0 = mb * 256 + wm * 64;
  const int c0 = nb * 128 + wn * 64;
#pragma unroll
  for (int mf = 0; mf < 4; ++mf)
#pragma unroll
    for (int nf = 0; nf < 4; ++nf)
#pragma unroll
      for (int r = 0; r < 4; ++r)
        Out[(size_t)(r0 + mf * 16 + lhi * 4 + r) * LDO + (c0 + nf * 16 + l15)] =
            acc[mf][nf][r];
#undef DST_A
#undef DST_B
}

extern "C" void kernel_launch(void* const* d_in, const int* in_sizes, int n_in,
                              void* d_out, int out_size, void* d_ws, size_t ws_size,
                              hipStream_t stream) {
  const float* x   = (const float*)d_in[0];   // [2,4096,3072] f32
  const float* w13 = (const float*)d_in[1];   // [16384,3072] f32
  const float* w2  = (const float*)d_in[2];   // [3072,8192] f32
  float* out = (float*)d_out;                 // [2,4096,3072] f32

  const size_t XB = 50331648, W13B = 100663296, W2B = 50331648;

  unsigned short* xb   = (unsigned short*)d_ws;
  unsigned short* w13b = (unsigned short*)((char*)d_ws + XB);
  unsigned short* w2b  = (unsigned short*)((char*)d_ws + XB + W13B);
  __hip_bfloat16* g    = (__hip_bfloat16*)((char*)d_ws + XB + W13B + W2B);

  k_cvt3<<<4096, 256, 0, stream>>>(x, w13, w2, xb, w13b, w2b);
  k_gateup19<<<2048, 512, 0, stream>>>(xb, w13b, g);
  k_down11<<<768, 512, 0, stream>>>((const unsigned short*)g, w2b, out);
}